// Round 1
// baseline (305.941 us; speedup 1.0000x reference)
//
#include <hip/hip_runtime.h>

// BNB 8-bit embedding dequant-gather:
//   out[t, :] = (float)q_weight[x[t], :] * (absmax[x[t]] / 127)
// B*S = 32768 tokens, DIM = 1024, VOCAB = 50257.
//
// NOTE: harness widens ALL integer inputs to int32 — q_weight arrives as
// int32 per element (NOT packed int8 bytes).
//
// Memory-bound: 128 MiB int32 gathered reads + 128 MiB fp32 writes
// (~268 MB -> ~43 us floor at 6.3 TB/s achievable).
//
// R2 structure: 8 tokens per block (4096 blocks x 256 threads).
//  - Phase-batched loads: 8x x[t] (scalar), then 8x absmax (scalar), then
//    8x row-gather int4 (vector) all in flight before first use -> 8-wide
//    memory-level parallelism instead of a serial x->absmax->row chain
//    per block.
//  - Non-temporal float4 stores: output is write-once; evict-first keeps
//    the 206 MB widened table resident in L2/L3 (table ~fits 256 MB L3),
//    improving gather hit rate for duplicate rows and across replays.

typedef __attribute__((ext_vector_type(4))) float f32x4;
typedef __attribute__((ext_vector_type(4))) int   i32x4;

#define TPB 8  // tokens per block

__global__ __launch_bounds__(256) void bnb8_embed_kernel(
    const int* __restrict__ x,
    const int* __restrict__ qw,      // widened int8 values, one int32 each
    const float* __restrict__ absmax,
    float* __restrict__ out,
    int dim,
    int n_tokens)
{
    const int t0 = blockIdx.x * TPB;          // first token of this block
    const int i  = threadIdx.x << 2;          // element offset within row

    // Phase 1: token ids (block-uniform addresses -> scalar loads, all
    // independent, issued together).
    int rows[TPB];
#pragma unroll
    for (int k = 0; k < TPB; ++k) {
        int t = t0 + k;
        rows[k] = x[t < n_tokens ? t : n_tokens - 1];
    }

    // Phase 2: per-row scales (uniform gather -> scalar loads, independent).
    float scales[TPB];
#pragma unroll
    for (int k = 0; k < TPB; ++k)
        scales[k] = absmax[rows[k]] * (1.0f / 127.0f);

    // Phase 3: all 8 row gathers in flight (16 B/lane each, 4 KiB/block
    // contiguous per token) before any result is consumed.
    i32x4 q[TPB];
#pragma unroll
    for (int k = 0; k < TPB; ++k)
        q[k] = *(const i32x4*)(qw + (size_t)rows[k] * (size_t)dim + i);

    // Phase 4: dequant + non-temporal store (evict-first, keep table cached).
#pragma unroll
    for (int k = 0; k < TPB; ++k) {
        int t = t0 + k;
        if (t >= n_tokens) break;             // block-uniform branch
        f32x4 o;
        o.x = (float)q[k].x * scales[k];
        o.y = (float)q[k].y * scales[k];
        o.z = (float)q[k].z * scales[k];
        o.w = (float)q[k].w * scales[k];
        __builtin_nontemporal_store(
            o, (f32x4*)(out + (size_t)t * (size_t)dim + i));
    }
}

extern "C" void kernel_launch(void* const* d_in, const int* in_sizes, int n_in,
                              void* d_out, int out_size, void* d_ws, size_t ws_size,
                              hipStream_t stream) {
    const int*   x      = (const int*)d_in[0];    // [B*S] int32
    const int*   qw     = (const int*)d_in[1];    // [VOCAB*DIM] int32 (widened int8)
    const float* absmax = (const float*)d_in[2];  // [VOCAB] f32
    float*       out    = (float*)d_out;          // [B*S*DIM] f32

    const int n_tokens = in_sizes[0];
    const int dim = out_size / n_tokens;          // 1024
    const int threads = dim / 4;                  // 256 lanes, 4 elems each
    const int blocks = (n_tokens + TPB - 1) / TPB;

    bnb8_embed_kernel<<<blocks, threads, 0, stream>>>(x, qw, absmax, out,
                                                      dim, n_tokens);
}